// Round 1
// baseline (221.478 us; speedup 1.0000x reference)
//
#include <hip/hip_runtime.h>

// Problem geometry (fixed by the reference)
#define HSZ 256
#define WSZ 256
#define BC  16          // b*c = 2*8
#define NCH 64          // 8x8 window -> 64 channels
#define PADLO 3         // reflect pad (3,4)

// Tiling
#define TW 64           // output tile width  (one wave per row)
#define TH 4            // output tile height (4 waves per block)
#define TROWS (TH + 7)  // 11 halo rows
#define TCOLS (TW + 7)  // 71 halo cols

__device__ __forceinline__ int reflect_idx(int i) {
    i = (i < 0) ? -i : i;                  // reflect (edge excluded), pad<=4
    i = (i >= HSZ) ? (2 * (HSZ - 1) - i) : i;
    return i;
}

// ---------------------------------------------------------------------------
// Kernel 1: build A = prod_i (I - 2 v_i v_i^T / ||v_i||^2) via rank-1 updates.
// Row r of A only ever needs row r and v_i -> each of 64 lanes owns one row
// in registers; no synchronization required. Result written to d_ws.
// ---------------------------------------------------------------------------
__global__ void build_A_kernel(const float* __restrict__ v, float* __restrict__ A) {
    const int r = threadIdx.x;  // 0..63
    float row[64];
#pragma unroll
    for (int c = 0; c < 64; ++c) row[c] = (c == r) ? 1.0f : 0.0f;

    for (int i = 0; i < 64; ++i) {
        float s = 0.0f, av = 0.0f;
#pragma unroll
        for (int c = 0; c < 64; ++c) {
            float vc = v[i * 64 + c];      // uniform address -> s_load
            s  += vc * vc;
            av += row[c] * vc;
        }
        const float scale = 2.0f * av / s;
#pragma unroll
        for (int c = 0; c < 64; ++c) row[c] -= scale * v[i * 64 + c];
    }
#pragma unroll
    for (int c = 0; c < 64; ++c) A[r * 64 + c] = row[c];
}

// ---------------------------------------------------------------------------
// Kernel 2: per output pixel, out[m] = sum_k patch[k] * A[k][m].
// Input tile staged in LDS (halo + reflect). Patch held in 64 VGPRs (static
// indices only). A read through wave-uniform global loads -> SGPRs.
// ---------------------------------------------------------------------------
__global__ __launch_bounds__(256)
void ortho_fold_kernel(const float* __restrict__ x,
                       const float* __restrict__ Ag,
                       float* __restrict__ out) {
    __shared__ float tile[TROWS][TCOLS];

    const int b  = blockIdx.z;
    const int y0 = blockIdx.y * TH;
    const int x0 = blockIdx.x * TW;

    const float* __restrict__ xb = x + (size_t)b * (HSZ * WSZ);

    // Cooperative halo load with reflect padding.
    const int tid = threadIdx.y * TW + threadIdx.x;
    for (int idx = tid; idx < TROWS * TCOLS; idx += TW * TH) {
        const int r  = idx / TCOLS;
        const int c  = idx - r * TCOLS;
        const int gr = reflect_idx(y0 + r - PADLO);
        const int gc = reflect_idx(x0 + c - PADLO);
        tile[r][c] = xb[gr * WSZ + gc];
    }
    __syncthreads();

    const int tx = threadIdx.x;   // 0..63  (lane == x within tile row)
    const int ty = threadIdx.y;   // 0..3   (wave == tile row)

    // 8x8 patch into registers; all indices compile-time -> stays in VGPRs.
    float patch[64];
#pragma unroll
    for (int k1 = 0; k1 < 8; ++k1)
#pragma unroll
        for (int k2 = 0; k2 < 8; ++k2)
            patch[k1 * 8 + k2] = tile[ty + k1][tx + k2];

    float* __restrict__ outb =
        out + (size_t)b * NCH * (HSZ * WSZ) + (size_t)(y0 + ty) * WSZ + (x0 + tx);

    // 4 passes of 16 channels: 16 fp32 accumulators, k fully unrolled so
    // patch[] indexing is static; A[k*64+mc+m] is wave-uniform -> s_load.
    for (int mc = 0; mc < 64; mc += 16) {
        float acc[16];
#pragma unroll
        for (int m = 0; m < 16; ++m) acc[m] = 0.0f;
#pragma unroll
        for (int k = 0; k < 64; ++k) {
            const float p = patch[k];
#pragma unroll
            for (int m = 0; m < 16; ++m)
                acc[m] = fmaf(p, Ag[k * 64 + mc + m], acc[m]);
        }
#pragma unroll
        for (int m = 0; m < 16; ++m)
            outb[(size_t)(mc + m) * (HSZ * WSZ)] = acc[m];  // 256B coalesced/wave
    }
}

// ---------------------------------------------------------------------------
extern "C" void kernel_launch(void* const* d_in, const int* in_sizes, int n_in,
                              void* d_out, int out_size, void* d_ws, size_t ws_size,
                              hipStream_t stream) {
    const float* x = (const float*)d_in[0];   // [2,8,256,256] fp32
    const float* v = (const float*)d_in[1];   // [64,64] fp32
    float* outp = (float*)d_out;              // [16,64,256,256] fp32
    float* A    = (float*)d_ws;               // 64*64 fp32 = 16 KB scratch

    build_A_kernel<<<1, 64, 0, stream>>>(v, A);

    dim3 grid(WSZ / TW, HSZ / TH, BC);        // 4 x 64 x 16 = 4096 blocks
    dim3 block(TW, TH);                       // 256 threads
    ortho_fold_kernel<<<grid, block, 0, stream>>>(x, A, outp);
}

// Round 2
// 139.990 us; speedup vs baseline: 1.5821x; 1.5821x over previous
//
#include <hip/hip_runtime.h>

// Problem geometry
#define HSZ 256
#define WSZ 256
#define BC  16          // b*c
#define NCH 64          // 8x8 window channels
#define PADLO 3         // reflect pad (3,4)

// Tiling: block = 4 waves; wave w computes output row y0+w, 64 consecutive cols
#define TW 64
#define TH 4
#define TR 11           // TH + 7 halo rows
#define TC 71           // TW + 7 halo cols
#define TSTRIDE 80      // padded row stride (floats): 16B-aligned rows, room for x4 overread

typedef short bf16x8 __attribute__((ext_vector_type(8)));
typedef float f32x4  __attribute__((ext_vector_type(4)));

__device__ __forceinline__ int reflect_idx(int i) {
    i = (i < 0) ? -i : i;
    i = (i >= HSZ) ? (2 * (HSZ - 1) - i) : i;
    return i;
}

// fp32 -> bf16 round-to-nearest-even
__device__ __forceinline__ unsigned short f2bf(float f) {
    unsigned u = __builtin_bit_cast(unsigned, f);
    u += 0x7FFFu + ((u >> 16) & 1u);
    return (unsigned short)(u >> 16);
}

// ---------------------------------------------------------------------------
// Kernel 1: build A = prod_i (I - 2 v_i v_i^T/||v_i||^2), then emit bf16
// A-operand fragments for mfma_f32_16x16x32_bf16, laid out so kernel 2 does
// one 16B vector load per fragment.
//   A-frag(mb, c): lane l, elem j = Aop[m = l&15][k = c*32 + (l>>4)*8 + j]
//   with Aop[m][k] = A[k][mb*16 + m]   (D = Aop * patches)
// ws layout: ushort frags[4][2][64][8]  (8 KB)
// ---------------------------------------------------------------------------
__global__ void build_A_frags(const float* __restrict__ v,
                              unsigned short* __restrict__ frags) {
    __shared__ float As[64][64];
    const int t = threadIdx.x;  // 0..63, one row of A per lane
    float row[64];
#pragma unroll
    for (int c = 0; c < 64; ++c) row[c] = (c == t) ? 1.0f : 0.0f;

    for (int i = 0; i < 64; ++i) {
        float s = 0.0f, av = 0.0f;
#pragma unroll
        for (int c = 0; c < 64; ++c) {
            float vc = v[i * 64 + c];
            s  += vc * vc;
            av += row[c] * vc;
        }
        const float scale = 2.0f * av / s;
#pragma unroll
        for (int c = 0; c < 64; ++c) row[c] -= scale * v[i * 64 + c];
    }
#pragma unroll
    for (int c = 0; c < 64; ++c) As[t][c] = row[c];
    __syncthreads();

    const int ln = t & 15, lh = t >> 4;
#pragma unroll
    for (int mb = 0; mb < 4; ++mb)
#pragma unroll
        for (int c = 0; c < 2; ++c)
#pragma unroll
            for (int j = 0; j < 8; ++j) {
                float val = As[c * 32 + lh * 8 + j][mb * 16 + ln];
                frags[(((mb * 2 + c) * 64) + t) * 8 + j] = f2bf(val);
            }
}

// ---------------------------------------------------------------------------
// Kernel 2: im2col-free MFMA. Per wave: one output row y, 64 cols.
// D[16x16] = Aop(16x32) x patches(32x16), K-chunks c=0,1, m-blocks mb=0..3,
// pixel groups g=0..3 (group g = pixels x0 + 4n + g, n = lane&15) so each
// lane's 4 group-results for a channel are 4 consecutive pixels -> float4 store.
// B-frag source: lane reads 16 consecutive fp32 from LDS row (aligned b128 x4),
// converts to bf16 once; group g's fragment = elems [g..g+7].
// ---------------------------------------------------------------------------
__global__ __launch_bounds__(256)
void ortho_mfma_kernel(const float* __restrict__ x,
                       const unsigned short* __restrict__ frags,
                       float* __restrict__ out) {
    __shared__ float tile[TR][TSTRIDE];

    const int b  = blockIdx.z;
    const int y0 = blockIdx.y * TH;
    const int x0 = blockIdx.x * TW;
    const float* __restrict__ xb = x + (size_t)b * (HSZ * WSZ);

    const int tx = threadIdx.x;   // lane 0..63
    const int ty = threadIdx.y;   // wave 0..3
    const int tid = ty * TW + tx;

    // Stage halo tile with reflect padding.
    for (int idx = tid; idx < TR * TC; idx += TW * TH) {
        const int r  = idx / TC;
        const int c  = idx - r * TC;
        tile[r][c] = xb[reflect_idx(y0 + r - PADLO) * WSZ + reflect_idx(x0 + c - PADLO)];
    }
    __syncthreads();

    const int ln = tx & 15, lh = tx >> 4;
    const int y  = y0 + ty;

    // Load 16 fp32 per k-chunk (row ty + 4c + lh, cols 4*ln .. 4*ln+15), cvt bf16.
    unsigned short bfv[2][16];
#pragma unroll
    for (int c = 0; c < 2; ++c) {
        const f32x4* rp = (const f32x4*)&tile[ty + 4 * c + lh][4 * ln];
        f32x4 q0 = rp[0], q1 = rp[1], q2 = rp[2], q3 = rp[3];
        float fl[16];
#pragma unroll
        for (int j = 0; j < 4; ++j) { fl[j] = q0[j]; fl[4 + j] = q1[j]; fl[8 + j] = q2[j]; fl[12 + j] = q3[j]; }
#pragma unroll
        for (int j = 0; j < 16; ++j) bfv[c][j] = f2bf(fl[j]);
    }

    // B fragments: chunk c, group g -> elems [g .. g+7]
    bf16x8 bfrag[2][4];
#pragma unroll
    for (int c = 0; c < 2; ++c)
#pragma unroll
        for (int g = 0; g < 4; ++g)
#pragma unroll
            for (int j = 0; j < 8; ++j)
                bfrag[c][g][j] = (short)bfv[c][g + j];

    float* __restrict__ outb =
        out + (size_t)b * NCH * (HSZ * WSZ) + (size_t)y * WSZ + x0 + 4 * ln;

#pragma unroll
    for (int mb = 0; mb < 4; ++mb) {
        const bf16x8 af0 = *(const bf16x8*)(frags + ((mb * 2 + 0) * 64 + tx) * 8);
        const bf16x8 af1 = *(const bf16x8*)(frags + ((mb * 2 + 1) * 64 + tx) * 8);

        f32x4 acc[4];
#pragma unroll
        for (int g = 0; g < 4; ++g) {
            acc[g] = (f32x4){0.0f, 0.0f, 0.0f, 0.0f};
            acc[g] = __builtin_amdgcn_mfma_f32_16x16x32_bf16(af0, bfrag[0][g], acc[g], 0, 0, 0);
            acc[g] = __builtin_amdgcn_mfma_f32_16x16x32_bf16(af1, bfrag[1][g], acc[g], 0, 0, 0);
        }

        // Store: channel ch = mb*16 + lh*4 + r; pixels x0 + 4*ln + {0,1,2,3}
#pragma unroll
        for (int r = 0; r < 4; ++r) {
            const int ch = mb * 16 + lh * 4 + r;
            f32x4 vv = { acc[0][r], acc[1][r], acc[2][r], acc[3][r] };
            *(f32x4*)&outb[(size_t)ch * (HSZ * WSZ)] = vv;
        }
    }
}

// ---------------------------------------------------------------------------
extern "C" void kernel_launch(void* const* d_in, const int* in_sizes, int n_in,
                              void* d_out, int out_size, void* d_ws, size_t ws_size,
                              hipStream_t stream) {
    const float* x = (const float*)d_in[0];       // [2,8,256,256] fp32
    const float* v = (const float*)d_in[1];       // [64,64] fp32
    float* outp = (float*)d_out;                  // [16,64,256,256] fp32
    unsigned short* frags = (unsigned short*)d_ws;// 4*2*64*8 bf16 = 8 KB

    build_A_frags<<<1, 64, 0, stream>>>(v, frags);

    dim3 grid(WSZ / TW, HSZ / TH, BC);            // 4 x 64 x 16
    dim3 block(TW, TH);                           // 256 threads = 4 waves
    ortho_mfma_kernel<<<grid, block, 0, stream>>>(x, frags, outp);
}

// Round 4
// 80.471 us; speedup vs baseline: 2.7523x; 1.7396x over previous
//
#include <hip/hip_runtime.h>

// Problem geometry
#define HSZ 256
#define WSZ 256
#define BC  16          // b*c
#define NCH 64          // 8x8 window channels
#define PADLO 3         // reflect pad (3,4)

// Tiling: block = 256 threads = 4 waves; wave w computes rows y0+2w, y0+2w+1
#define TW 64
#define TH 8
#define NTHR 256        // actual block size (TW * TH/2) — staging stride!
#define TR 15           // TH + 7 halo rows
#define TC 71           // TW + 7 halo cols
#define TSTRIDE 80      // padded row stride (floats); 16B-aligned, room for x4 overread

typedef short bf16x8 __attribute__((ext_vector_type(8)));
typedef float f32x4  __attribute__((ext_vector_type(4)));

__device__ __forceinline__ int reflect_idx(int i) {
    i = (i < 0) ? -i : i;
    i = (i >= HSZ) ? (2 * (HSZ - 1) - i) : i;
    return i;
}

// fp32 -> bf16 round-to-nearest-even
__device__ __forceinline__ unsigned short f2bf(float f) {
    unsigned u = __builtin_bit_cast(unsigned, f);
    u += 0x7FFFu + ((u >> 16) & 1u);
    return (unsigned short)(u >> 16);
}

// ---------------------------------------------------------------------------
// Kernel 1: A = prod_i (I - 2 v_i v_i^T/||v_i||^2), 256 threads.
// 4 lanes per row (lane owns 16 columns); dots reduced via shfl_xor(16,32).
// Wave w then emits bf16 A-fragments for m-block mb=w:
//   frag(mb,c): lane l, elem j = A[k = c*32 + (l>>4)*8 + j][mb*16 + (l&15)]
// ws layout: ushort frags[4][2][64][8]  (8 KB)
// ---------------------------------------------------------------------------
__global__ void build_A_frags(const float* __restrict__ v,
                              unsigned short* __restrict__ frags) {
    __shared__ float As[64][64];
    const int t = threadIdx.x;        // 0..255
    const int w = t >> 6;             // wave 0..3
    const int l = t & 63;             // lane
    const int r = (w << 4) | (l & 15);// row of A owned (with 3 partner lanes)
    const int q = l >> 4;             // column quarter 0..3

    float row[16];
#pragma unroll
    for (int c = 0; c < 16; ++c) row[c] = (q * 16 + c == r) ? 1.0f : 0.0f;

    for (int i = 0; i < 64; ++i) {
        const f32x4* vp = (const f32x4*)(v + i * 64 + q * 16);
        f32x4 v0 = vp[0], v1 = vp[1], v2 = vp[2], v3 = vp[3];
        float vv[16];
#pragma unroll
        for (int j = 0; j < 4; ++j) { vv[j] = v0[j]; vv[4+j] = v1[j]; vv[8+j] = v2[j]; vv[12+j] = v3[j]; }

        float s0 = 0, s1 = 0, s2 = 0, s3 = 0, a0 = 0, a1 = 0, a2 = 0, a3 = 0;
#pragma unroll
        for (int c = 0; c < 4; ++c) {
            s0 = fmaf(vv[c],      vv[c],      s0);
            s1 = fmaf(vv[4+c],    vv[4+c],    s1);
            s2 = fmaf(vv[8+c],    vv[8+c],    s2);
            s3 = fmaf(vv[12+c],   vv[12+c],   s3);
            a0 = fmaf(row[c],     vv[c],      a0);
            a1 = fmaf(row[4+c],   vv[4+c],    a1);
            a2 = fmaf(row[8+c],   vv[8+c],    a2);
            a3 = fmaf(row[12+c],  vv[12+c],   a3);
        }
        float s  = (s0 + s1) + (s2 + s3);
        float av = (a0 + a1) + (a2 + a3);
        av += __shfl_xor(av, 16); s += __shfl_xor(s, 16);
        av += __shfl_xor(av, 32); s += __shfl_xor(s, 32);

        const float scale = 2.0f * av / s;
#pragma unroll
        for (int c = 0; c < 16; ++c) row[c] = fmaf(-scale, vv[c], row[c]);
    }
#pragma unroll
    for (int c = 0; c < 16; ++c) As[r][q * 16 + c] = row[c];
    __syncthreads();

    const int ln = l & 15, lh = l >> 4;
    const int mb = w;
#pragma unroll
    for (int c2 = 0; c2 < 2; ++c2)
#pragma unroll
        for (int j = 0; j < 8; ++j) {
            float val = As[c2 * 32 + lh * 8 + j][mb * 16 + ln];
            frags[(((mb * 2 + c2) * 64) + l) * 8 + j] = f2bf(val);
        }
}

// ---------------------------------------------------------------------------
// Kernel 2: per wave, 2 output rows x 64 cols x 64 ch via mfma_f32_16x16x32_bf16.
// Pixel groups g: lane's 4 group-results per channel = 4 consecutive px ->
// nontemporal float4 store (write-once streaming output; don't thrash L2).
// ---------------------------------------------------------------------------
__global__ __launch_bounds__(256)
void ortho_mfma_kernel(const float* __restrict__ x,
                       const unsigned short* __restrict__ frags,
                       float* __restrict__ out) {
    __shared__ float tile[TR][TSTRIDE];

    const int b  = blockIdx.z;
    const int y0 = blockIdx.y * TH;
    const int x0 = blockIdx.x * TW;
    const float* __restrict__ xb = x + (size_t)b * (HSZ * WSZ);

    const int tx = threadIdx.x;   // lane 0..63
    const int ty = threadIdx.y;   // wave 0..3
    const int tid = ty * TW + tx;

    // Stage halo tile with reflect padding. Stride = ACTUAL block size (256).
    for (int idx = tid; idx < TR * TC; idx += NTHR) {
        const int r  = idx / TC;
        const int c  = idx - r * TC;
        tile[r][c] = xb[reflect_idx(y0 + r - PADLO) * WSZ + reflect_idx(x0 + c - PADLO)];
    }

    const int ln = tx & 15, lh = tx >> 4;

    // Hoist A fragments (8 x 16B, L2-hot, reused for both rows)
    bf16x8 af[4][2];
#pragma unroll
    for (int mb = 0; mb < 4; ++mb)
#pragma unroll
        for (int c = 0; c < 2; ++c)
            af[mb][c] = *(const bf16x8*)(frags + ((mb * 2 + c) * 64 + tx) * 8);

    __syncthreads();

#pragma unroll
    for (int ry = 0; ry < 2; ++ry) {
        const int tyr = ty * 2 + ry;           // tile-row of this output row
        const int y   = y0 + tyr;

        // 16 consecutive fp32 per k-chunk -> bf16 once
        unsigned short bfv[2][16];
#pragma unroll
        for (int c = 0; c < 2; ++c) {
            const f32x4* rp = (const f32x4*)&tile[tyr + 4 * c + lh][4 * ln];
            f32x4 q0 = rp[0], q1 = rp[1], q2 = rp[2], q3 = rp[3];
            float fl[16];
#pragma unroll
            for (int j = 0; j < 4; ++j) { fl[j] = q0[j]; fl[4+j] = q1[j]; fl[8+j] = q2[j]; fl[12+j] = q3[j]; }
#pragma unroll
            for (int j = 0; j < 16; ++j) bfv[c][j] = f2bf(fl[j]);
        }

        // B fragments: chunk c, pixel-group g -> elems [g .. g+7]
        bf16x8 bfrag[2][4];
#pragma unroll
        for (int c = 0; c < 2; ++c)
#pragma unroll
            for (int g = 0; g < 4; ++g)
#pragma unroll
                for (int j = 0; j < 8; ++j)
                    bfrag[c][g][j] = (short)bfv[c][g + j];

        float* __restrict__ outb =
            out + (size_t)b * NCH * (HSZ * WSZ) + (size_t)y * WSZ + x0 + 4 * ln;

#pragma unroll
        for (int mb = 0; mb < 4; ++mb) {
            f32x4 acc[4];
#pragma unroll
            for (int g = 0; g < 4; ++g) {
                acc[g] = (f32x4){0.0f, 0.0f, 0.0f, 0.0f};
                acc[g] = __builtin_amdgcn_mfma_f32_16x16x32_bf16(af[mb][0], bfrag[0][g], acc[g], 0, 0, 0);
                acc[g] = __builtin_amdgcn_mfma_f32_16x16x32_bf16(af[mb][1], bfrag[1][g], acc[g], 0, 0, 0);
            }
#pragma unroll
            for (int r = 0; r < 4; ++r) {
                const int ch = mb * 16 + lh * 4 + r;
                f32x4 vv = { acc[0][r], acc[1][r], acc[2][r], acc[3][r] };
                __builtin_nontemporal_store(vv, (f32x4*)&outb[(size_t)ch * (HSZ * WSZ)]);
            }
        }
    }
}

// ---------------------------------------------------------------------------
extern "C" void kernel_launch(void* const* d_in, const int* in_sizes, int n_in,
                              void* d_out, int out_size, void* d_ws, size_t ws_size,
                              hipStream_t stream) {
    const float* x = (const float*)d_in[0];        // [2,8,256,256] fp32
    const float* v = (const float*)d_in[1];        // [64,64] fp32
    float* outp = (float*)d_out;                   // [16,64,256,256] fp32
    unsigned short* frags = (unsigned short*)d_ws; // 4*2*64*8 bf16 = 8 KB

    build_A_frags<<<1, 256, 0, stream>>>(v, frags);

    dim3 grid(WSZ / TW, HSZ / TH, BC);             // 4 x 32 x 16 = 2048 blocks
    dim3 block(TW, TH / 2);                        // 256 threads = 4 waves
    ortho_mfma_kernel<<<grid, block, 0, stream>>>(x, frags, outp);
}